// Round 1
// baseline (1048.872 us; speedup 1.0000x reference)
//
#include <hip/hip_runtime.h>
#include <stdint.h>

// Problem constants
#define DM   1024      // d_model
#define NH   16        // heads
#define DKq  64        // d_key = d_value
#define NB   8         // batch
#define SS   512       // seq len
#define BS   (NB*SS)   // 4096 rows
#define BHN  (NB*NH)   // 128 (b,h) pairs

typedef __attribute__((ext_vector_type(8))) short bf16x8;   // 8 bf16 in 4 VGPRs
typedef __attribute__((ext_vector_type(4))) float f32x4;

__device__ __forceinline__ float bf2f(unsigned short u){
    return __uint_as_float(((unsigned int)u) << 16);
}
__device__ __forceinline__ unsigned short f2bf(float f){
    unsigned int u = __float_as_uint(f);
    u = u + 0x7fffu + ((u >> 16) & 1u);   // round-to-nearest-even
    return (unsigned short)(u >> 16);
}

// ---------------------------------------------------------------- casts
__global__ __launch_bounds__(256) void cast_f32_bf16(const float* __restrict__ src,
                                                     unsigned short* __restrict__ dst, int n4){
    int i = blockIdx.x * 256 + threadIdx.x;
    if (i < n4){
        float4 v = ((const float4*)src)[i];
        uint2 o;
        o.x = (unsigned int)f2bf(v.x) | ((unsigned int)f2bf(v.y) << 16);
        o.y = (unsigned int)f2bf(v.z) | ((unsigned int)f2bf(v.w) << 16);
        ((uint2*)dst)[i] = o;
    }
}

// dst[c][k] = bf16(src[k][c])  (store W^T so MFMA B-fragments are k-contiguous)
__global__ __launch_bounds__(256) void transpose_cast(const float* __restrict__ src,
                                                      unsigned short* __restrict__ dst,
                                                      int R, int C){
    __shared__ float tile[32][33];
    int c0 = blockIdx.x * 32, r0 = blockIdx.y * 32;
    int tx = threadIdx.x, ty = threadIdx.y;   // block (32,8)
    for (int r = ty; r < 32; r += 8) tile[r][tx] = src[(size_t)(r0 + r) * C + (c0 + tx)];
    __syncthreads();
    for (int r = ty; r < 32; r += 8) dst[(size_t)(c0 + r) * R + (r0 + tx)] = f2bf(tile[tx][r]);
}

// ---------------------------------------------------------------- GEMM (bf16 MFMA, 64x64 tile, BK=64)
// A[M,K] row-major bf16; Bt[N,K] = B^T row-major bf16. 4 waves = 2x2, each wave 32x32 (2x2 frags).
// MODE 0: QKV epilogue -> scatter to Q/K/V [bh][s][64] bf16 (+bias). MODE 1: fp32 out (+bias).
#define GP 88   // LDS row pad: 88 shorts = 176 B (16B aligned, 2-way-max bank alias)
template<int MODE>
__global__ __launch_bounds__(256) void gemm64(const unsigned short* __restrict__ A,
        const unsigned short* __restrict__ Bt, int K,
        unsigned short* __restrict__ oq, unsigned short* __restrict__ okk, unsigned short* __restrict__ ov,
        const float* __restrict__ bz0, const float* __restrict__ bz1, const float* __restrict__ bz2,
        float* __restrict__ ofp, const float* __restrict__ bo)
{
    __shared__ unsigned short As[64 * GP];
    __shared__ unsigned short Bs[64 * GP];
    const int t = threadIdx.x;
    const int m0 = blockIdx.x * 64, n0 = blockIdx.y * 64;
    const int lane = t & 63, w = t >> 6;
    const int wr = w >> 1, wc = w & 1;
    const int lr = lane & 15, lg = lane >> 4;
    const int sm = t >> 3, skq = t & 7;    // staging: 32 rows x 8 chunks

    f32x4 acc[2][2];
    for (int a = 0; a < 2; ++a) for (int b = 0; b < 2; ++b) acc[a][b] = (f32x4){0.f, 0.f, 0.f, 0.f};

    for (int kk = 0; kk < K; kk += 64){
        for (int p = 0; p < 2; ++p){
            int m = sm + p * 32;
            *(uint4*)(&As[m * GP + skq * 8]) = *(const uint4*)(A  + (size_t)(m0 + m) * K + kk + skq * 8);
            *(uint4*)(&Bs[m * GP + skq * 8]) = *(const uint4*)(Bt + (size_t)(n0 + m) * K + kk + skq * 8);
        }
        __syncthreads();
        for (int kh = 0; kh < 2; ++kh){
            bf16x8 a0 = *(const bf16x8*)(&As[(wr * 32 +  0 + lr) * GP + kh * 32 + lg * 8]);
            bf16x8 a1 = *(const bf16x8*)(&As[(wr * 32 + 16 + lr) * GP + kh * 32 + lg * 8]);
            bf16x8 b0 = *(const bf16x8*)(&Bs[(wc * 32 +  0 + lr) * GP + kh * 32 + lg * 8]);
            bf16x8 b1 = *(const bf16x8*)(&Bs[(wc * 32 + 16 + lr) * GP + kh * 32 + lg * 8]);
            acc[0][0] = __builtin_amdgcn_mfma_f32_16x16x32_bf16(a0, b0, acc[0][0], 0, 0, 0);
            acc[0][1] = __builtin_amdgcn_mfma_f32_16x16x32_bf16(a0, b1, acc[0][1], 0, 0, 0);
            acc[1][0] = __builtin_amdgcn_mfma_f32_16x16x32_bf16(a1, b0, acc[1][0], 0, 0, 0);
            acc[1][1] = __builtin_amdgcn_mfma_f32_16x16x32_bf16(a1, b1, acc[1][1], 0, 0, 0);
        }
        __syncthreads();
    }
    // epilogue: D col = lane&15, row = (lane>>4)*4 + r  [m89-verified]
    for (int fr = 0; fr < 2; ++fr)
    for (int fc = 0; fc < 2; ++fc){
        int col = n0 + wc * 32 + fc * 16 + lr;
        for (int r = 0; r < 4; ++r){
            int row = m0 + wr * 32 + fr * 16 + lg * 4 + r;
            float v = acc[fr][fc][r];
            if (MODE == 0){
                int sel = col >> 10, cw = col & 1023;
                const float* bp = (sel == 0) ? bz0 : (sel == 1 ? bz1 : bz2);
                v += bp[cw];
                int h = cw >> 6, d = cw & 63;
                int b_ = row >> 9, s = row & 511;
                unsigned short* dst = (sel == 0) ? oq : (sel == 1 ? okk : ov);
                dst[((size_t)(b_ * NH + h) * SS + s) * DKq + d] = f2bf(v);
            } else {
                ofp[(size_t)row * DM + col] = v + bo[col];
            }
        }
    }
}

// ---------------------------------------------------------------- fused attention
// Block = 8 bh x 8 query rows; online softmax over 32 j-tiles of 16.
// scores[bb,ii,j] = 0.125*( q.(K[bb,j]) + q.(ek[ii,j]) ) + bias ; ctx += P*(V[bb,j]+ev[ii,j])
#define BHG 8
#define ITB 8
#define JTB 16
#define SP  68   // fp32 row pad (272 B, 16B aligned)
#define STP 17

__global__ __launch_bounds__(256) void attn_kernel(
    const unsigned short* __restrict__ Qb,  // [bh][s][64] bf16
    const unsigned short* __restrict__ Kb,
    const unsigned short* __restrict__ Vb,
    const float* __restrict__ ekG,          // [S][S][64] f32
    const float* __restrict__ evG,
    const float* __restrict__ biasG,        // [bh][S][S] f32
    unsigned short* __restrict__ CTXb)      // [b*S+s][h*64+d] bf16
{
    __shared__ float Ksl[BHG * JTB * SP];   // K then V tile
    __shared__ float Esl[ITB * JTB * SP];   // ek then ev tile
    __shared__ float st [BHG * ITB * STP];  // bias -> scores -> P
    __shared__ float mrow[64], lrow[64], arow[64];

    const int t   = threadIdx.x;
    const int it  = blockIdx.x >> 4;        // i-tile (slow: 16 consecutive blocks share ek/ev stripe)
    const int bhg = blockIdx.x & 15;
    const int bh0 = bhg * 8, i0 = it * 8;

    // score-phase mapping: 4 lanes per (bb,ii) row, each lane owns 16 d's of q
    const int rowS = t >> 2, bbS = rowS >> 3, iiS = rowS & 7, sub = t & 3;
    // PV mapping: bbP = t>>5, lane owns d0,d0+1
    const int bbP = t >> 5;
    const int d0  = (t & 31) * 2;

    float qreg[16];
    {
        const unsigned short* qp = Qb + ((size_t)(bh0 + bbS) * SS + (i0 + iiS)) * DKq + sub * 16;
        uint4 u0 = *(const uint4*)(qp);
        uint4 u1 = *(const uint4*)(qp + 8);
        unsigned int uu[8] = {u0.x, u0.y, u0.z, u0.w, u1.x, u1.y, u1.z, u1.w};
        #pragma unroll
        for (int x = 0; x < 8; ++x){
            qreg[2 * x]     = bf2f((unsigned short)(uu[x] & 0xffffu));
            qreg[2 * x + 1] = bf2f((unsigned short)(uu[x] >> 16));
        }
    }
    if (t < 64){ mrow[t] = -1e30f; lrow[t] = 0.f; }
    float ctx[8][2];
    #pragma unroll
    for (int i = 0; i < 8; ++i){ ctx[i][0] = 0.f; ctx[i][1] = 0.f; }

    for (int jt = 0; jt < SS / JTB; ++jt){
        const int j0 = jt * JTB;
        __syncthreads();                       // prev-iter PV done with Ksl/Esl/st
        // ---- phase a: stage K(bf16->f32), ek(f32), bias->st
        #pragma unroll
        for (int p = 0; p < 4; ++p){
            int c = t + p * 256;               // 1024 8-elem chunks
            int row = c >> 3, kq = c & 7;
            int bb = row >> 4, jj = row & 15;
            uint4 u = *(const uint4*)(Kb + ((size_t)(bh0 + bb) * SS + (j0 + jj)) * DKq + kq * 8);
            unsigned int uu[4] = {u.x, u.y, u.z, u.w};
            float f[8];
            #pragma unroll
            for (int x = 0; x < 4; ++x){ f[2*x] = bf2f((unsigned short)(uu[x] & 0xffffu)); f[2*x+1] = bf2f((unsigned short)(uu[x] >> 16)); }
            float* dp = &Ksl[row * SP + kq * 8];
            *(float4*)(dp)     = make_float4(f[0], f[1], f[2], f[3]);
            *(float4*)(dp + 4) = make_float4(f[4], f[5], f[6], f[7]);
        }
        #pragma unroll
        for (int p = 0; p < 8; ++p){
            int c = t + p * 256;               // 2048 float4 chunks
            int row = c >> 4, q4 = c & 15;
            int ii = row >> 4, jj = row & 15;
            float4 v = *(const float4*)(ekG + ((size_t)(i0 + ii) * SS + (j0 + jj)) * DKq + q4 * 4);
            *(float4*)(&Esl[row * SP + q4 * 4]) = v;
        }
        #pragma unroll
        for (int p = 0; p < 4; ++p){
            int idx = t + p * 256;             // 1024 bias values
            int jj = idx & 15, ii = (idx >> 4) & 7, bb = idx >> 7;
            st[(bb * 8 + ii) * STP + jj] =
                biasG[(size_t)(bh0 + bb) * (SS * SS) + (size_t)(i0 + ii) * SS + (j0 + jj)];
        }
        __syncthreads();
        // ---- phase b: scores (content + edge share the q dot)
        for (int jj = 0; jj < JTB; ++jj){
            const float* kp = &Ksl[(bbS * JTB + jj) * SP + sub * 16];
            const float* ep = &Esl[(iiS * JTB + jj) * SP + sub * 16];
            float s = 0.f;
            #pragma unroll
            for (int x4 = 0; x4 < 4; ++x4){
                float4 k4 = *(const float4*)(kp + x4 * 4);
                float4 e4 = *(const float4*)(ep + x4 * 4);
                s += qreg[x4*4+0] * (k4.x + e4.x);
                s += qreg[x4*4+1] * (k4.y + e4.y);
                s += qreg[x4*4+2] * (k4.z + e4.z);
                s += qreg[x4*4+3] * (k4.w + e4.w);
            }
            s += __shfl_xor(s, 1);
            s += __shfl_xor(s, 2);
            if (sub == 0) st[rowS * STP + jj] += 0.125f * s;   // scale = 1/sqrt(64)
        }
        __syncthreads();
        // ---- phase c: online-softmax update (one thread per (bb,ii) row)
        if (t < 64){
            float mo = mrow[t], mx = mo;
            float sv[16];
            #pragma unroll
            for (int jj = 0; jj < 16; ++jj){ sv[jj] = st[t * STP + jj]; mx = fmaxf(mx, sv[jj]); }
            float al = __expf(mo - mx), sum = 0.f;
            #pragma unroll
            for (int jj = 0; jj < 16; ++jj){ float pv = __expf(sv[jj] - mx); st[t * STP + jj] = pv; sum += pv; }
            mrow[t] = mx; lrow[t] = al * lrow[t] + sum; arow[t] = al;
        }
        __syncthreads();
        // ---- phase d: rescale ctx, stage V/ev over K/ek
        #pragma unroll
        for (int ii = 0; ii < 8; ++ii){
            float al = arow[bbP * 8 + ii];
            ctx[ii][0] *= al; ctx[ii][1] *= al;
        }
        #pragma unroll
        for (int p = 0; p < 4; ++p){
            int c = t + p * 256;
            int row = c >> 3, kq = c & 7;
            int bb = row >> 4, jj = row & 15;
            uint4 u = *(const uint4*)(Vb + ((size_t)(bh0 + bb) * SS + (j0 + jj)) * DKq + kq * 8);
            unsigned int uu[4] = {u.x, u.y, u.z, u.w};
            float f[8];
            #pragma unroll
            for (int x = 0; x < 4; ++x){ f[2*x] = bf2f((unsigned short)(uu[x] & 0xffffu)); f[2*x+1] = bf2f((unsigned short)(uu[x] >> 16)); }
            float* dp = &Ksl[row * SP + kq * 8];
            *(float4*)(dp)     = make_float4(f[0], f[1], f[2], f[3]);
            *(float4*)(dp + 4) = make_float4(f[4], f[5], f[6], f[7]);
        }
        #pragma unroll
        for (int p = 0; p < 8; ++p){
            int c = t + p * 256;
            int row = c >> 4, q4 = c & 15;
            int ii = row >> 4, jj = row & 15;
            float4 v = *(const float4*)(evG + ((size_t)(i0 + ii) * SS + (j0 + jj)) * DKq + q4 * 4);
            *(float4*)(&Esl[row * SP + q4 * 4]) = v;
        }
        __syncthreads();
        // ---- phase e: PV accumulate
        #pragma unroll
        for (int ii = 0; ii < 8; ++ii){
            float c0a = ctx[ii][0], c1a = ctx[ii][1];
            for (int jj = 0; jj < JTB; ++jj){
                float p  = st[(bbP * 8 + ii) * STP + jj];
                float2 v2 = *(const float2*)(&Ksl[(bbP * JTB + jj) * SP + d0]);
                float2 e2 = *(const float2*)(&Esl[(ii  * JTB + jj) * SP + d0]);
                c0a += p * (v2.x + e2.x);
                c1a += p * (v2.y + e2.y);
            }
            ctx[ii][0] = c0a; ctx[ii][1] = c1a;
        }
    }
    // ---- epilogue: normalize, write ctx bf16 to [b*S+s][h*64+d]
    {
        int bh = bh0 + bbP;
        int b_ = bh >> 4, h = bh & 15;
        #pragma unroll
        for (int ii = 0; ii < 8; ++ii){
            float inv = 1.0f / lrow[bbP * 8 + ii];
            unsigned int pk = (unsigned int)f2bf(ctx[ii][0] * inv)
                            | ((unsigned int)f2bf(ctx[ii][1] * inv) << 16);
            *(unsigned int*)(&CTXb[(size_t)(b_ * SS + (i0 + ii)) * DM + h * DKq + d0]) = pk;
        }
    }
}

// ---------------------------------------------------------------- launch
extern "C" void kernel_launch(void* const* d_in, const int* in_sizes, int n_in,
                              void* d_out, int out_size, void* d_ws, size_t ws_size,
                              hipStream_t stream){
    const float* queries = (const float*)d_in[0];
    const float* ekG     = (const float*)d_in[1];
    const float* evG     = (const float*)d_in[2];
    const float* biasG   = (const float*)d_in[3];
    const float* Wq      = (const float*)d_in[4];
    const float* bq      = (const float*)d_in[5];
    const float* Wk      = (const float*)d_in[6];
    const float* bk      = (const float*)d_in[7];
    const float* Wv      = (const float*)d_in[8];
    const float* bv      = (const float*)d_in[9];
    const float* Wo      = (const float*)d_in[10];
    const float* bo      = (const float*)d_in[11];
    float* out = (float*)d_out;

    char* ws = (char*)d_ws;                       // layout (48 MB total):
    unsigned short* Xb   = (unsigned short*)(ws);                    //  8 MB bf16 X
    unsigned short* WbT  = (unsigned short*)(ws + (8u  << 20));      //  6 MB bf16 [Wq|Wk|Wv]^T
    unsigned short* WobT = (unsigned short*)(ws + (14u << 20));      //  2 MB bf16 Wo^T
    unsigned short* Qb   = (unsigned short*)(ws + (16u << 20));      //  8 MB
    unsigned short* Kb   = (unsigned short*)(ws + (24u << 20));      //  8 MB
    unsigned short* Vb   = (unsigned short*)(ws + (32u << 20));      //  8 MB
    unsigned short* CTXb = (unsigned short*)(ws + (40u << 20));      //  8 MB

    cast_f32_bf16<<<(BS * DM / 4 + 255) / 256, 256, 0, stream>>>(queries, Xb, BS * DM / 4);

    dim3 tb(32, 8);
    transpose_cast<<<dim3(32, 32), tb, 0, stream>>>(Wq, WbT,               1024, 1024);
    transpose_cast<<<dim3(32, 32), tb, 0, stream>>>(Wk, WbT + (1u << 20),  1024, 1024);
    transpose_cast<<<dim3(32, 32), tb, 0, stream>>>(Wv, WbT + (2u << 20),  1024, 1024);
    transpose_cast<<<dim3(32, 32), tb, 0, stream>>>(Wo, WobT,              1024, 1024);

    gemm64<0><<<dim3(64, 48), 256, 0, stream>>>(Xb, WbT, 1024,
            Qb, Kb, Vb, bq, bk, bv, nullptr, nullptr);

    attn_kernel<<<1024, 256, 0, stream>>>(Qb, Kb, Vb, ekG, evG, biasG, CTXb);

    gemm64<1><<<dim3(64, 16), 256, 0, stream>>>(CTXb, WobT, 1024,
            nullptr, nullptr, nullptr, nullptr, nullptr, nullptr, out, bo);
}

// Round 3
// 571.403 us; speedup vs baseline: 1.8356x; 1.8356x over previous
//
#include <hip/hip_runtime.h>
#include <hip/hip_fp16.h>
#include <stdint.h>

// Problem constants
#define DM   1024      // d_model
#define NH   16        // heads
#define DKq  64        // d_key = d_value
#define NB   8         // batch
#define SS   512       // seq len
#define BS   (NB*SS)   // 4096 rows
#define BHN  (NB*NH)   // 128 (b,h) pairs

typedef __attribute__((ext_vector_type(8))) short bf16x8;   // 8 bf16 in 4 VGPRs
typedef __attribute__((ext_vector_type(4))) float f32x4;

__device__ __forceinline__ float bf2f(unsigned short u){
    return __uint_as_float(((unsigned int)u) << 16);
}
__device__ __forceinline__ unsigned short f2bf(float f){
    unsigned int u = __float_as_uint(f);
    u = u + 0x7fffu + ((u >> 16) & 1u);   // round-to-nearest-even
    return (unsigned short)(u >> 16);
}

// ---------------------------------------------------------------- casts
__global__ __launch_bounds__(256) void cast_f32_bf16(const float* __restrict__ src,
                                                     unsigned short* __restrict__ dst, int n4){
    int i = blockIdx.x * 256 + threadIdx.x;
    if (i < n4){
        float4 v = ((const float4*)src)[i];
        uint2 o;
        o.x = (unsigned int)f2bf(v.x) | ((unsigned int)f2bf(v.y) << 16);
        o.y = (unsigned int)f2bf(v.z) | ((unsigned int)f2bf(v.w) << 16);
        ((uint2*)dst)[i] = o;
    }
}

// dst[c][k] = bf16(src[k][c])  (store W^T so MFMA B-fragments are k-contiguous)
__global__ __launch_bounds__(256) void transpose_cast(const float* __restrict__ src,
                                                      unsigned short* __restrict__ dst,
                                                      int R, int C){
    __shared__ float tile[32][33];
    int c0 = blockIdx.x * 32, r0 = blockIdx.y * 32;
    int tx = threadIdx.x, ty = threadIdx.y;   // block (32,8)
    for (int r = ty; r < 32; r += 8) tile[r][tx] = src[(size_t)(r0 + r) * C + (c0 + tx)];
    __syncthreads();
    for (int r = ty; r < 32; r += 8) dst[(size_t)(c0 + r) * R + (r0 + tx)] = f2bf(tile[tx][r]);
}

// ev f32 [i][j][d] -> evT bf16 [i][d][j]   (one block per (i, 64-j chunk))
__global__ __launch_bounds__(256) void trans_ev(const float* __restrict__ ev,
                                                unsigned short* __restrict__ evT){
    __shared__ float tile[64][68];
    const int t = threadIdx.x;
    const int i = blockIdx.x >> 3, jc = blockIdx.x & 7;
    #pragma unroll
    for (int p = 0; p < 4; ++p){
        int c = t + p * 256, row = c >> 4, seg = c & 15;
        *(float4*)&tile[row][seg * 4] = *(const float4*)(ev + ((size_t)i * SS + jc * 64 + row) * DKq + seg * 4);
    }
    __syncthreads();
    #pragma unroll
    for (int p = 0; p < 2; ++p){
        int c = t + p * 256, drow = c >> 3, jb = (c & 7) * 8;
        uint4 o;
        unsigned int pk[4];
        #pragma unroll
        for (int x = 0; x < 4; ++x)
            pk[x] = (unsigned int)f2bf(tile[jb + 2 * x][drow]) | ((unsigned int)f2bf(tile[jb + 2 * x + 1][drow]) << 16);
        o.x = pk[0]; o.y = pk[1]; o.z = pk[2]; o.w = pk[3];
        *(uint4*)(evT + ((size_t)i * DKq + drow) * SS + jc * 64 + jb) = o;
    }
}

// Vb bf16 [bh][s][d] -> Vt bf16 [bh][d][s]   (one block per (bh, 64-s chunk))
__global__ __launch_bounds__(256) void trans_v(const unsigned short* __restrict__ Vb,
                                               unsigned short* __restrict__ Vt){
    __shared__ unsigned short tile[64][72];
    const int t = threadIdx.x;
    const int bh = blockIdx.x >> 3, jc = blockIdx.x & 7;
    #pragma unroll
    for (int p = 0; p < 2; ++p){
        int c = t + p * 256, row = c >> 3, seg = c & 7;
        *(uint4*)&tile[row][seg * 8] = *(const uint4*)(Vb + ((size_t)bh * SS + jc * 64 + row) * DKq + seg * 8);
    }
    __syncthreads();
    #pragma unroll
    for (int p = 0; p < 2; ++p){
        int c = t + p * 256, drow = c >> 3, jb = (c & 7) * 8;
        uint4 o;
        unsigned int pk[4];
        #pragma unroll
        for (int x = 0; x < 4; ++x)
            pk[x] = (unsigned int)tile[jb + 2 * x][drow] | (((unsigned int)tile[jb + 2 * x + 1][drow]) << 16);
        o.x = pk[0]; o.y = pk[1]; o.z = pk[2]; o.w = pk[3];
        *(uint4*)(Vt + ((size_t)bh * DKq + drow) * SS + jc * 64 + jb) = o;
    }
}

// ---------------------------------------------------------------- GEMM (bf16 MFMA, 64x64 tile, BK=64)
#define GP 88
template<int MODE>
__global__ __launch_bounds__(256) void gemm64(const unsigned short* __restrict__ A,
        const unsigned short* __restrict__ Bt, int K,
        unsigned short* __restrict__ oq, unsigned short* __restrict__ okk, unsigned short* __restrict__ ov,
        unsigned short* __restrict__ qi,
        const float* __restrict__ bz0, const float* __restrict__ bz1, const float* __restrict__ bz2,
        float* __restrict__ ofp, const float* __restrict__ bo)
{
    __shared__ unsigned short As[64 * GP];
    __shared__ unsigned short Bs[64 * GP];
    const int t = threadIdx.x;
    const int m0 = blockIdx.x * 64, n0 = blockIdx.y * 64;
    const int lane = t & 63, w = t >> 6;
    const int wr = w >> 1, wc = w & 1;
    const int lr = lane & 15, lg = lane >> 4;
    const int sm = t >> 3, skq = t & 7;

    f32x4 acc[2][2];
    for (int a = 0; a < 2; ++a) for (int b = 0; b < 2; ++b) acc[a][b] = (f32x4){0.f, 0.f, 0.f, 0.f};

    for (int kk = 0; kk < K; kk += 64){
        for (int p = 0; p < 2; ++p){
            int m = sm + p * 32;
            *(uint4*)(&As[m * GP + skq * 8]) = *(const uint4*)(A  + (size_t)(m0 + m) * K + kk + skq * 8);
            *(uint4*)(&Bs[m * GP + skq * 8]) = *(const uint4*)(Bt + (size_t)(n0 + m) * K + kk + skq * 8);
        }
        __syncthreads();
        for (int kh = 0; kh < 2; ++kh){
            bf16x8 a0 = *(const bf16x8*)(&As[(wr * 32 +  0 + lr) * GP + kh * 32 + lg * 8]);
            bf16x8 a1 = *(const bf16x8*)(&As[(wr * 32 + 16 + lr) * GP + kh * 32 + lg * 8]);
            bf16x8 b0 = *(const bf16x8*)(&Bs[(wc * 32 +  0 + lr) * GP + kh * 32 + lg * 8]);
            bf16x8 b1 = *(const bf16x8*)(&Bs[(wc * 32 + 16 + lr) * GP + kh * 32 + lg * 8]);
            acc[0][0] = __builtin_amdgcn_mfma_f32_16x16x32_bf16(a0, b0, acc[0][0], 0, 0, 0);
            acc[0][1] = __builtin_amdgcn_mfma_f32_16x16x32_bf16(a0, b1, acc[0][1], 0, 0, 0);
            acc[1][0] = __builtin_amdgcn_mfma_f32_16x16x32_bf16(a1, b0, acc[1][0], 0, 0, 0);
            acc[1][1] = __builtin_amdgcn_mfma_f32_16x16x32_bf16(a1, b1, acc[1][1], 0, 0, 0);
        }
        __syncthreads();
    }
    for (int fr = 0; fr < 2; ++fr)
    for (int fc = 0; fc < 2; ++fc){
        int col = n0 + wc * 32 + fc * 16 + lr;
        for (int r = 0; r < 4; ++r){
            int row = m0 + wr * 32 + fr * 16 + lg * 4 + r;
            float v = acc[fr][fc][r];
            if (MODE == 0){
                int sel = col >> 10, cw = col & 1023;
                const float* bp = (sel == 0) ? bz0 : (sel == 1 ? bz1 : bz2);
                v += bp[cw];
                int h = cw >> 6, d = cw & 63;
                int b_ = row >> 9, s = row & 511;
                unsigned short* dst = (sel == 0) ? oq : (sel == 1 ? okk : ov);
                unsigned short bv = f2bf(v);
                dst[((size_t)(b_ * NH + h) * SS + s) * DKq + d] = bv;
                if (sel == 0)  // extra Q copy in [i][bh][d] layout for es_kernel
                    qi[((size_t)s * BHN + (b_ * NH + h)) * DKq + d] = bv;
            } else {
                ofp[(size_t)row * DM + col] = v + bo[col];
            }
        }
    }
}

// ---------------------------------------------------------------- edge scores + bias (per i: [128 bh] x [512 j])
// ESh[bh][i][j] = f16( 0.125 * (Qi[i][bh,:] . ekb[i][j,:]) + bias[bh][i][j] )
__global__ __launch_bounds__(256) void es_kernel(
    const unsigned short* __restrict__ Qi,   // [i][bh][d] bf16
    const unsigned short* __restrict__ ekb,  // [i][j][d]  bf16
    const float* __restrict__ biasG,         // [bh][i][j] f32
    unsigned short* __restrict__ ESh)        // [bh][i][j] f16
{
    __shared__ unsigned short Aly[128 * 72];
    __shared__ unsigned short Bly[128 * 72];
    const int t = threadIdx.x;
    const int i = blockIdx.x >> 2, j0 = (blockIdx.x & 3) * 128;
    const int lane = t & 63, w = t >> 6;
    const int wr = w >> 1, wc = w & 1;
    const int lr = lane & 15, lg = lane >> 4;

    #pragma unroll
    for (int p = 0; p < 4; ++p){
        int c = t + p * 256, row = c >> 3, seg = c & 7;
        *(uint4*)&Aly[row * 72 + seg * 8] = *(const uint4*)(Qi + (size_t)i * (BHN * DKq) + c * 8);
        *(uint4*)&Bly[row * 72 + seg * 8] = *(const uint4*)(ekb + ((size_t)i * SS + j0 + row) * DKq + seg * 8);
    }
    __syncthreads();

    f32x4 acc[4][4];
    #pragma unroll
    for (int m = 0; m < 4; ++m)
        #pragma unroll
        for (int n = 0; n < 4; ++n) acc[m][n] = (f32x4){0.f, 0.f, 0.f, 0.f};

    #pragma unroll
    for (int kh = 0; kh < 2; ++kh){
        bf16x8 a[4], b[4];
        #pragma unroll
        for (int m = 0; m < 4; ++m) a[m] = *(const bf16x8*)&Aly[(wr * 64 + m * 16 + lr) * 72 + kh * 32 + lg * 8];
        #pragma unroll
        for (int n = 0; n < 4; ++n) b[n] = *(const bf16x8*)&Bly[(wc * 64 + n * 16 + lr) * 72 + kh * 32 + lg * 8];
        #pragma unroll
        for (int m = 0; m < 4; ++m)
            #pragma unroll
            for (int n = 0; n < 4; ++n)
                acc[m][n] = __builtin_amdgcn_mfma_f32_16x16x32_bf16(a[m], b[n], acc[m][n], 0, 0, 0);
    }

    #pragma unroll
    for (int m = 0; m < 4; ++m)
    #pragma unroll
    for (int n = 0; n < 4; ++n){
        int j = j0 + wc * 64 + n * 16 + lr;
        #pragma unroll
        for (int r = 0; r < 4; ++r){
            int bh = wr * 64 + m * 16 + lg * 4 + r;
            float v = acc[m][n][r] * 0.125f + biasG[(size_t)bh * (SS * SS) + (size_t)i * SS + j];
            ESh[(size_t)bh * (SS * SS) + (size_t)i * SS + j] = __half_as_ushort(__float2half(v));
        }
    }
}

// ---------------------------------------------------------------- fused content attention (MFMA) + exact softmax
// block = (bh, 32-row i-tile). Writes normalized P to Pb[i][bh][j] bf16 and content ctx to CTXf f32.
__global__ __launch_bounds__(256) void attn2(
    const unsigned short* __restrict__ Qb,   // [bh][s][d]
    const unsigned short* __restrict__ Kb,   // [bh][s][d]
    const unsigned short* __restrict__ Vt,   // [bh][d][s]
    const unsigned short* __restrict__ ESh,  // [bh][i][j] f16
    unsigned short* __restrict__ Pb,         // [i][bh][j] bf16
    float* __restrict__ CTXf)                // [b*S+s][h*64+d]
{
    __shared__ unsigned short Qs[32 * 72];
    __shared__ unsigned short Ks[64 * 72];   // K tile, then V^T tile
    __shared__ unsigned short SP[32 * 520];  // scores f16, then P bf16 (in place)

    const int t = threadIdx.x;
    const int bh = blockIdx.x >> 4, i0 = (blockIdx.x & 15) * 32;
    const int w = t >> 6, lane = t & 63, lr = lane & 15, lg = lane >> 4;
    const int b_ = bh >> 4, h = bh & 15;

    {   // Q tile 32x64
        int row = t >> 3, seg = t & 7;
        *(uint4*)&Qs[row * 72 + seg * 8] = *(const uint4*)(Qb + ((size_t)bh * SS + i0 + row) * DKq + seg * 8);
    }

    // ---- content scores; S = 0.125*QK^T + ES  -> f16 LDS
    for (int jt = 0; jt < 8; ++jt){
        const int j0 = jt * 64;
        __syncthreads();
        #pragma unroll
        for (int p = 0; p < 2; ++p){
            int c = t + p * 256, row = c >> 3, seg = c & 7;
            *(uint4*)&Ks[row * 72 + seg * 8] = *(const uint4*)(Kb + ((size_t)bh * SS + j0 + row) * DKq + seg * 8);
        }
        __syncthreads();
        f32x4 acc[2] = {(f32x4){0.f,0.f,0.f,0.f}, (f32x4){0.f,0.f,0.f,0.f}};
        #pragma unroll
        for (int kh = 0; kh < 2; ++kh){
            bf16x8 b = *(const bf16x8*)&Ks[(w * 16 + lr) * 72 + kh * 32 + lg * 8];
            #pragma unroll
            for (int m = 0; m < 2; ++m){
                bf16x8 a = *(const bf16x8*)&Qs[(m * 16 + lr) * 72 + kh * 32 + lg * 8];
                acc[m] = __builtin_amdgcn_mfma_f32_16x16x32_bf16(a, b, acc[m], 0, 0, 0);
            }
        }
        int jc = j0 + w * 16 + lr;
        #pragma unroll
        for (int m = 0; m < 2; ++m){
            const unsigned short* esp = ESh + (size_t)bh * (SS * SS) + (size_t)(i0 + m * 16 + lg * 4) * SS + jc;
            #pragma unroll
            for (int r = 0; r < 4; ++r){
                float sv = acc[m][r] * 0.125f + __half2float(__ushort_as_half(esp[(size_t)r * SS]));
                SP[(m * 16 + lg * 4 + r) * 520 + jc] = __half_as_ushort(__float2half(sv));
            }
        }
    }
    __syncthreads();

    // ---- exact softmax over full 512-row (8 lanes per row), P -> bf16 in place + global
    {
        const int row = t >> 3, sub = t & 7;
        uint4 u[8];
        #pragma unroll
        for (int x = 0; x < 8; ++x) u[x] = *(const uint4*)&SP[row * 520 + x * 64 + sub * 8];
        float mx = -1e30f;
        #pragma unroll
        for (int x = 0; x < 8; ++x){
            unsigned int ww[4] = {u[x].x, u[x].y, u[x].z, u[x].w};
            #pragma unroll
            for (int q = 0; q < 4; ++q){
                mx = fmaxf(mx, __half2float(__ushort_as_half((unsigned short)(ww[q] & 0xffffu))));
                mx = fmaxf(mx, __half2float(__ushort_as_half((unsigned short)(ww[q] >> 16))));
            }
        }
        mx = fmaxf(mx, __shfl_xor(mx, 1));
        mx = fmaxf(mx, __shfl_xor(mx, 2));
        mx = fmaxf(mx, __shfl_xor(mx, 4));
        float sum = 0.f;
        #pragma unroll
        for (int x = 0; x < 8; ++x){
            unsigned int ww[4] = {u[x].x, u[x].y, u[x].z, u[x].w};
            #pragma unroll
            for (int q = 0; q < 4; ++q){
                sum += __expf(__half2float(__ushort_as_half((unsigned short)(ww[q] & 0xffffu))) - mx);
                sum += __expf(__half2float(__ushort_as_half((unsigned short)(ww[q] >> 16))) - mx);
            }
        }
        sum += __shfl_xor(sum, 1);
        sum += __shfl_xor(sum, 2);
        sum += __shfl_xor(sum, 4);
        const float inv = 1.0f / sum;
        unsigned short* pgl = Pb + ((size_t)(i0 + row) * BHN + bh) * SS;
        #pragma unroll
        for (int x = 0; x < 8; ++x){
            unsigned int ww[4] = {u[x].x, u[x].y, u[x].z, u[x].w};
            uint4 o;
            unsigned int pk[4];
            #pragma unroll
            for (int q = 0; q < 4; ++q){
                float p0 = __expf(__half2float(__ushort_as_half((unsigned short)(ww[q] & 0xffffu))) - mx) * inv;
                float p1 = __expf(__half2float(__ushort_as_half((unsigned short)(ww[q] >> 16))) - mx) * inv;
                pk[q] = (unsigned int)f2bf(p0) | ((unsigned int)f2bf(p1) << 16);
            }
            o.x = pk[0]; o.y = pk[1]; o.z = pk[2]; o.w = pk[3];
            *(uint4*)&SP[row * 520 + x * 64 + sub * 8] = o;
            *(uint4*)(pgl + x * 64 + sub * 8) = o;
        }
    }

    // ---- content PV: ctx[i][d] = sum_j P[i][j] V[j][d]  (B = V^T tile from Vt)
    f32x4 cacc[2] = {(f32x4){0.f,0.f,0.f,0.f}, (f32x4){0.f,0.f,0.f,0.f}};
    for (int jt = 0; jt < 8; ++jt){
        const int j0 = jt * 64;
        __syncthreads();
        #pragma unroll
        for (int p = 0; p < 2; ++p){
            int c = t + p * 256, row = c >> 3, seg = c & 7;
            *(uint4*)&Ks[row * 72 + seg * 8] = *(const uint4*)(Vt + ((size_t)bh * DKq + row) * SS + j0 + seg * 8);
        }
        __syncthreads();
        #pragma unroll
        for (int kh = 0; kh < 2; ++kh){
            bf16x8 b = *(const bf16x8*)&Ks[(w * 16 + lr) * 72 + kh * 32 + lg * 8];
            #pragma unroll
            for (int m = 0; m < 2; ++m){
                bf16x8 a = *(const bf16x8*)&SP[(m * 16 + lr) * 520 + j0 + kh * 32 + lg * 8];
                cacc[m] = __builtin_amdgcn_mfma_f32_16x16x32_bf16(a, b, cacc[m], 0, 0, 0);
            }
        }
    }
    {
        const int d = w * 16 + lr;
        #pragma unroll
        for (int m = 0; m < 2; ++m)
            #pragma unroll
            for (int r = 0; r < 4; ++r){
                int i = i0 + m * 16 + lg * 4 + r;
                CTXf[((size_t)b_ * SS + i) * DM + h * DKq + d] = cacc[m][r];
            }
    }
}

// ---------------------------------------------------------------- edge PV + combine
// per i: ctxE[bh][d] = P_i[bh][j] . evT_i[d][j]^T ; CTXb = bf16(CTXf + ctxE)
__global__ __launch_bounds__(256) void edgepv(
    const unsigned short* __restrict__ Pb,   // [i][bh][j]
    const unsigned short* __restrict__ evT,  // [i][d][j]
    const float* __restrict__ CTXf,
    unsigned short* __restrict__ CTXb)
{
    __shared__ unsigned short Pa[128 * 72];
    __shared__ unsigned short Eb[64 * 72];
    const int t = threadIdx.x, i = blockIdx.x;
    const int w = t >> 6, lane = t & 63, lr = lane & 15, lg = lane >> 4;

    f32x4 acc[2][4];
    #pragma unroll
    for (int m = 0; m < 2; ++m)
        #pragma unroll
        for (int n = 0; n < 4; ++n) acc[m][n] = (f32x4){0.f, 0.f, 0.f, 0.f};

    for (int kt = 0; kt < 8; ++kt){
        const int j0 = kt * 64;
        __syncthreads();
        #pragma unroll
        for (int p = 0; p < 4; ++p){
            int c = t + p * 256, row = c >> 3, seg = c & 7;
            *(uint4*)&Pa[row * 72 + seg * 8] = *(const uint4*)(Pb + ((size_t)i * BHN + row) * SS + j0 + seg * 8);
        }
        #pragma unroll
        for (int p = 0; p < 2; ++p){
            int c = t + p * 256, row = c >> 3, seg = c & 7;
            *(uint4*)&Eb[row * 72 + seg * 8] = *(const uint4*)(evT + ((size_t)i * DKq + row) * SS + j0 + seg * 8);
        }
        __syncthreads();
        #pragma unroll
        for (int kh = 0; kh < 2; ++kh){
            bf16x8 b[4];
            #pragma unroll
            for (int n = 0; n < 4; ++n) b[n] = *(const bf16x8*)&Eb[(n * 16 + lr) * 72 + kh * 32 + lg * 8];
            #pragma unroll
            for (int m = 0; m < 2; ++m){
                bf16x8 a = *(const bf16x8*)&Pa[(w * 32 + m * 16 + lr) * 72 + kh * 32 + lg * 8];
                #pragma unroll
                for (int n = 0; n < 4; ++n)
                    acc[m][n] = __builtin_amdgcn_mfma_f32_16x16x32_bf16(a, b[n], acc[m][n], 0, 0, 0);
            }
        }
    }
    #pragma unroll
    for (int m = 0; m < 2; ++m)
    #pragma unroll
    for (int n = 0; n < 4; ++n){
        int d = n * 16 + lr;
        #pragma unroll
        for (int r = 0; r < 4; ++r){
            int bh = w * 32 + m * 16 + lg * 4 + r;
            size_t idx = ((size_t)(bh >> 4) * SS + i) * DM + (bh & 15) * DKq + d;
            CTXb[idx] = f2bf(acc[m][n][r] + CTXf[idx]);
        }
    }
}

// ---------------------------------------------------------------- launch
extern "C" void kernel_launch(void* const* d_in, const int* in_sizes, int n_in,
                              void* d_out, int out_size, void* d_ws, size_t ws_size,
                              hipStream_t stream){
    const float* queries = (const float*)d_in[0];
    const float* ekG     = (const float*)d_in[1];
    const float* evG     = (const float*)d_in[2];
    const float* biasG   = (const float*)d_in[3];
    const float* Wq      = (const float*)d_in[4];
    const float* bq      = (const float*)d_in[5];
    const float* Wk      = (const float*)d_in[6];
    const float* bk      = (const float*)d_in[7];
    const float* Wv      = (const float*)d_in[8];
    const float* bv      = (const float*)d_in[9];
    const float* Wo      = (const float*)d_in[10];
    const float* bo      = (const float*)d_in[11];
    float* out = (float*)d_out;

    char* ws = (char*)d_ws;
    const size_t MB = (size_t)1 << 20;
    unsigned short* Xb   = (unsigned short*)(ws);              //   0..8   bf16 X
    unsigned short* WbT  = (unsigned short*)(ws + 8   * MB);   //   8..14  [Wq|Wk|Wv]^T bf16
    unsigned short* WobT = (unsigned short*)(ws + 14  * MB);   //  14..16  Wo^T bf16
    unsigned short* Qb   = (unsigned short*)(ws + 16  * MB);   //  16..24  Q [bh][s][d]
    unsigned short* Kb   = (unsigned short*)(ws + 24  * MB);   //  24..32  K [bh][s][d]
    unsigned short* Vb   = (unsigned short*)(ws + 32  * MB);   //  32..40  V [bh][s][d]
    unsigned short* CTXb = (unsigned short*)(ws + 40  * MB);   //  40..48  ctx bf16 [b*S+s][h*64+d]
    unsigned short* Qi   = (unsigned short*)(ws + 48  * MB);   //  48..56  Q [i][bh][d]
    unsigned short* ekb  = (unsigned short*)(ws + 56  * MB);   //  56..88  ek bf16 [i][j][d]  (dead after es_kernel)
    float*          CTXf = (float*)         (ws + 56  * MB);   //  56..72  content ctx f32 (overlays dead ekb)
    unsigned short* evT  = (unsigned short*)(ws + 88  * MB);   //  88..120 ev^T bf16 [i][d][j]
    unsigned short* Vt   = (unsigned short*)(ws + 120 * MB);   // 120..128 V^T bf16 [bh][d][s]
    unsigned short* ESh  = (unsigned short*)(ws + 128 * MB);   // 128..192 edge scores + bias f16 [bh][i][j]
    unsigned short* Pb   = (unsigned short*)(ws + 192 * MB);   // 192..256 P bf16 [i][bh][j]

    cast_f32_bf16<<<(BS * DM / 4 + 255) / 256, 256, 0, stream>>>(queries, Xb, BS * DM / 4);

    dim3 tb(32, 8);
    transpose_cast<<<dim3(32, 32), tb, 0, stream>>>(Wq, WbT,               1024, 1024);
    transpose_cast<<<dim3(32, 32), tb, 0, stream>>>(Wk, WbT + (1u << 20),  1024, 1024);
    transpose_cast<<<dim3(32, 32), tb, 0, stream>>>(Wv, WbT + (2u << 20),  1024, 1024);
    transpose_cast<<<dim3(32, 32), tb, 0, stream>>>(Wo, WobT,              1024, 1024);

    cast_f32_bf16<<<(SS * SS * DKq / 4 + 255) / 256, 256, 0, stream>>>(ekG, ekb, SS * SS * DKq / 4);
    trans_ev<<<SS * 8, 256, 0, stream>>>(evG, evT);

    gemm64<0><<<dim3(64, 48), 256, 0, stream>>>(Xb, WbT, 1024,
            Qb, Kb, Vb, Qi, bq, bk, bv, nullptr, nullptr);

    trans_v<<<BHN * 8, 256, 0, stream>>>(Vb, Vt);

    es_kernel<<<SS * 4, 256, 0, stream>>>(Qi, ekb, biasG, ESh);

    attn2<<<BHN * 16, 256, 0, stream>>>(Qb, Kb, Vt, ESh, Pb, CTXf);

    edgepv<<<SS, 256, 0, stream>>>(Pb, evT, CTXf, CTXb);

    gemm64<1><<<dim3(64, 16), 256, 0, stream>>>(CTXb, WobT, 1024,
            nullptr, nullptr, nullptr, nullptr, nullptr, nullptr, nullptr, out, bo);
}